// Round 8
// baseline (33.671 us; speedup 1.0000x reference)
//
#include <hip/hip_runtime.h>

// Chamfer distance, B=4, N=M=8192, fp32 in R^3 — MFMA, role-swapped.
//
// d_ij = |y_j|^2 - 2 x_i.y_j + |x_i|^2 via v_mfma_f32_32x32x16_bf16,
// split-bf16 (13 of 16 K-slots; xl*yl dropped ~2^-18).
// A = STREAMED y rows (LDS), B = FIXED x cols (2 frags/wave).
// C/D: col=lane&31, row=(reg&3)+8*(reg>>2)+4*half => lane's 16 regs = 16 rows
// of ONE column => row-min = in-lane min3 tree (8 min3/MFMA) into 1 scalar.
//
// R6 post-mortem: live set ~75 VGPR vs launch_bounds(256,8) cap of 64 =>
// compiler spilled/shuttled inside the hot loop. R7: time-share ONE d
// register block (d = mfma(bf0); reduce; d = mfma(bf1); reduce) => live ~52,
// honest 8 waves/SIMD. Cross-wave overlap keeps the matrix pipe saturated
// (per-wave MFMA duty 64cy/~200cy x 8 waves > 1).

#define BATCH 4
#define NPTS 8192
#define TPB 256
#define NFRAG 2
#define COLS_PER_WAVE 64                  // NFRAG * 32
#define COLS_PER_BLOCK 256                // 4 waves
#define XBLKS (NPTS / COLS_PER_BLOCK)     // 32
#define YSEGS 8
#define YSEG (NPTS / YSEGS)               // 1024
#define CHUNK 512
#define NCHUNK (YSEG / CHUNK)             // 2
#define JT (CHUNK / 32)                   // 16

typedef __attribute__((ext_vector_type(8))) short bf16x8;
typedef __attribute__((ext_vector_type(16))) float f32x16;
union FragU { int4 i4; bf16x8 v; };

__device__ inline unsigned short bf16_rne(float f) {
    unsigned int u = __float_as_uint(f);
    return (unsigned short)((u + 0x7FFFu + ((u >> 16) & 1u)) >> 16);
}
__device__ inline float bf16_f32(unsigned short h) {
    return __uint_as_float(((unsigned int)h) << 16);
}
__device__ inline unsigned int pack2(unsigned int lo, unsigned int hi) {
    return (lo & 0xFFFFu) | (hi << 16);
}

// ---- prepack: frag both roles; also init keys + zero the reduce counter ----
__global__ __launch_bounds__(256) void prepack_kernel(
    const float* __restrict__ xyz1, const float* __restrict__ xyz2,
    int4* __restrict__ rowpack, int4* __restrict__ colpack,
    unsigned int* __restrict__ keys, unsigned int* __restrict__ counter)
{
    const int id  = blockIdx.x * 256 + threadIdx.x;    // [0, 65536)
    const int arr = id >> 15;
    const int rem = id & 32767;                         // b*8192+n
    const float* p = (arr ? xyz2 : xyz1) + (size_t)rem * 3;
    const float x0 = p[0], x1 = p[1], x2 = p[2];

    keys[id] = 0xFFFFFFFFu;                             // exactly 2*B*N threads
    if (id == 0) *counter = 0;

    const unsigned short h0 = bf16_rne(x0), h1 = bf16_rne(x1), h2 = bf16_rne(x2);
    const unsigned short l0 = bf16_rne(x0 - bf16_f32(h0));
    const unsigned short l1 = bf16_rne(x1 - bf16_f32(h1));
    const unsigned short l2 = bf16_rne(x2 - bf16_f32(h2));
    const float s = x0 * x0 + x1 * x1 + x2 * x2;
    const unsigned short sh = bf16_rne(s);
    const unsigned short sl = bf16_rne(s - bf16_f32(sh));
    const unsigned short one = 0x3F80;

    // row role: [h0,h1,h2,h0,h1,h2,l0,l1 | l2,one,one,sh,sl,0,0,0]
    int4 rlo, rhi;
    rlo.x = pack2(h0, h1); rlo.y = pack2(h2, h0);
    rlo.z = pack2(h1, h2); rlo.w = pack2(l0, l1);
    rhi.x = pack2(l2, one); rhi.y = pack2(one, sh);
    rhi.z = pack2(sl, 0u);  rhi.w = 0;
    rowpack[2 * id]     = rlo;
    rowpack[2 * id + 1] = rhi;

    // col role: g=-2x: [gh0,gh1,gh2,gl0,gl1,gl2,gh0,gh1 | gh2,sh,sl,one,one,0,0,0]
    const float g0 = -2.0f * x0, g1 = -2.0f * x1, g2 = -2.0f * x2;
    const unsigned short gh0 = bf16_rne(g0), gh1 = bf16_rne(g1), gh2 = bf16_rne(g2);
    const unsigned short gl0 = bf16_rne(g0 - bf16_f32(gh0));
    const unsigned short gl1 = bf16_rne(g1 - bf16_f32(gh1));
    const unsigned short gl2 = bf16_rne(g2 - bf16_f32(gh2));
    int4 clo, chi;
    clo.x = pack2(gh0, gh1); clo.y = pack2(gh2, gl0);
    clo.z = pack2(gl1, gl2); clo.w = pack2(gh0, gh1);
    chi.x = pack2(gh2, sh);  chi.y = pack2(sl, one);
    chi.z = pack2(one, 0u);  chi.w = 0;
    colpack[2 * id]     = clo;
    colpack[2 * id + 1] = chi;
}

__device__ inline float red16(float cb, const f32x16& d) {
    const float m0 = fminf(fminf(d[0],  d[1]),  d[2]);
    const float m1 = fminf(fminf(d[3],  d[4]),  d[5]);
    const float m2 = fminf(fminf(d[6],  d[7]),  d[8]);
    const float m3 = fminf(fminf(d[9],  d[10]), d[11]);
    const float m4 = fminf(fminf(d[12], d[13]), d[14]);
    const float u0 = fminf(fminf(m0, m1), m2);
    const float u1 = fminf(fminf(m3, m4), d[15]);
    return fminf(fminf(cb, u0), u1);
}

__global__ __launch_bounds__(TPB, 8) void chamfer_main(
    const int4* __restrict__ rowpack,
    const int4* __restrict__ colpack,
    unsigned int* __restrict__ keys)
{
    const int blk  = blockIdx.x;
    const int seg  = blk & (YSEGS - 1);
    const int xblk = (blk >> 3) & (XBLKS - 1);
    const int b    = (blk >> 8) & (BATCH - 1);
    const int dir  = blk >> 10;
    const int arrB = dir;        // cols = array whose dist we output
    const int arrA = dir ^ 1;    // rows = the other array, streamed

    const int t = threadIdx.x, lane = t & 63, wave = t >> 6;
    const int half = lane >> 5, l31 = lane & 31;

    __shared__ int4 sb0[CHUNK];   // half0 row-frags
    __shared__ int4 sb1[CHUNK];   // half1 row-frags

    // fixed B fragments: 2 x-col tiles per wave
    const int xbase = xblk * COLS_PER_BLOCK + wave * COLS_PER_WAVE;
    const size_t cb_idx = ((size_t)(arrB * BATCH + b) * NPTS + xbase) * 2;
    FragU bf0, bf1;
    bf0.i4 = colpack[cb_idx + (size_t)(0 * 32 + l31) * 2 + half];
    bf1.i4 = colpack[cb_idx + (size_t)(1 * 32 + l31) * 2 + half];

    float cb0 = __builtin_inff();
    float cb1 = __builtin_inff();
    const f32x16 zero = {0.0f, 0.0f, 0.0f, 0.0f, 0.0f, 0.0f, 0.0f, 0.0f,
                         0.0f, 0.0f, 0.0f, 0.0f, 0.0f, 0.0f, 0.0f, 0.0f};

    const size_t rbase = ((size_t)(arrA * BATCH + b) * NPTS + (size_t)seg * YSEG) * 2;

    for (int c = 0; c < NCHUNK; ++c) {
        __syncthreads();
        {
            // copy 512 prepacked row-frags (2 pts / thread, 64B coalesced)
            const int4* src = rowpack + rbase + (size_t)c * CHUNK * 2 + (size_t)t * 4;
            const int4 a0 = src[0], a1 = src[1], a2 = src[2], a3 = src[3];
            sb0[2 * t]     = a0;  sb1[2 * t]     = a1;
            sb0[2 * t + 1] = a2;  sb1[2 * t + 1] = a3;
        }
        __syncthreads();

        const int4* asrc = half ? sb1 : sb0;
#pragma unroll 4
        for (int jt = 0; jt < JT; ++jt) {
            FragU af; af.i4 = asrc[jt * 32 + l31];
            // time-share ONE 16-reg d block: live set stays ~52 VGPR
            f32x16 d = __builtin_amdgcn_mfma_f32_32x32x16_bf16(af.v, bf0.v, zero, 0, 0, 0);
            asm volatile("" :: "v"(d));   // keep in arch VGPRs (no AGPR shuttle)
            cb0 = red16(cb0, d);
            d = __builtin_amdgcn_mfma_f32_32x32x16_bf16(af.v, bf1.v, zero, 0, 0, 0);
            asm volatile("" :: "v"(d));
            cb1 = red16(cb1, d);
        }
    }

    // epilogue: combine the two halves (same cols), one atomic per frag
    unsigned int* ok = keys + ((size_t)dir * BATCH + b) * NPTS + xbase;
    {
        const float v0 = fminf(cb0, __shfl_xor(cb0, 32, 64));
        const float v1 = fminf(cb1, __shfl_xor(cb1, 32, 64));
        if (half == 0) {
            unsigned int u = __float_as_uint(v0);
            atomicMin(&ok[l31], u ^ ((u >> 31) ? 0xFFFFFFFFu : 0x80000000u));
            u = __float_as_uint(v1);
            atomicMin(&ok[32 + l31], u ^ ((u >> 31) ? 0xFFFFFFFFu : 0x80000000u));
        }
    }
}

__device__ inline float key_decode(unsigned int key) {
    const unsigned int u = (key & 0x80000000u) ? (key ^ 0x80000000u) : ~key;
    return __uint_as_float(u);
}

// 8 blocks x 1024 threads; each thread owns one uint4 of each direction.
// Partials via device-scope atomics (coherent point, XCD-safe); the last
// block to increment the counter sums partials in fixed order.
__global__ __launch_bounds__(1024) void reduce_kernel(
    const unsigned int* __restrict__ keys,
    unsigned long long* __restrict__ partials,   // 16 slots
    unsigned int* __restrict__ counter,
    float* __restrict__ out)
{
    const uint4* v1 = (const uint4*)keys;                    // dir 0
    const uint4* v2 = (const uint4*)(keys + BATCH * NPTS);   // dir 1
    const int idx = blockIdx.x * 1024 + threadIdx.x;         // [0, 8192)
    const uint4 a = v1[idx];
    const uint4 c = v2[idx];
    double s1 = (double)key_decode(a.x) + (double)key_decode(a.y)
              + (double)key_decode(a.z) + (double)key_decode(a.w);
    double s2 = (double)key_decode(c.x) + (double)key_decode(c.y)
              + (double)key_decode(c.z) + (double)key_decode(c.w);
    for (int off = 32; off > 0; off >>= 1) {
        s1 += __shfl_down(s1, off, 64);
        s2 += __shfl_down(s2, off, 64);
    }
    __shared__ double l1[16], l2[16];
    const int wave = threadIdx.x >> 6;
    if ((threadIdx.x & 63) == 0) { l1[wave] = s1; l2[wave] = s2; }
    __syncthreads();
    if (threadIdx.x == 0) {
        double t1 = 0.0, t2 = 0.0;
        for (int w = 0; w < 16; ++w) { t1 += l1[w]; t2 += l2[w]; }
        atomicExch(&partials[2 * blockIdx.x],     (unsigned long long)__double_as_longlong(t1));
        atomicExch(&partials[2 * blockIdx.x + 1], (unsigned long long)__double_as_longlong(t2));
        __threadfence();
        const unsigned int old = atomicAdd(counter, 1u);
        if (old == 7u) {   // last block: finalize in fixed order (deterministic)
            double g1 = 0.0, g2 = 0.0;
            for (int w = 0; w < 8; ++w) {
                g1 += __longlong_as_double((long long)atomicAdd(&partials[2 * w],     0ull));
                g2 += __longlong_as_double((long long)atomicAdd(&partials[2 * w + 1], 0ull));
            }
            const double n = (double)(BATCH * NPTS);
            out[0] = (float)(g1 / n + g2 / n);
        }
    }
}

extern "C" void kernel_launch(void* const* d_in, const int* in_sizes, int n_in,
                              void* d_out, int out_size, void* d_ws, size_t ws_size,
                              hipStream_t stream) {
    const float* xyz1 = (const float*)d_in[0];
    const float* xyz2 = (const float*)d_in[1];
    float* out = (float*)d_out;

    int4* rowpack = (int4*)d_ws;                                  // 2 MB
    int4* colpack = rowpack + 2 * 65536;                          // 2 MB
    unsigned int* keys = (unsigned int*)(colpack + 2 * 65536);    // 256 KB
    unsigned long long* partials = (unsigned long long*)(keys + 2 * BATCH * NPTS);
    unsigned int* counter = (unsigned int*)(partials + 16);

    prepack_kernel<<<256, 256, 0, stream>>>(xyz1, xyz2, rowpack, colpack, keys, counter);

    chamfer_main<<<2 * BATCH * XBLKS * YSEGS, TPB, 0, stream>>>(rowpack, colpack, keys);

    reduce_kernel<<<8, 1024, 0, stream>>>(keys, partials, counter, out);
}